// Round 13
// baseline (24.665 us; speedup 1.0000x reference)
//
#include <hip/hip_runtime.h>
#include <hip/hip_bf16.h>

#define B_    2048
#define OBS_  1024
#define A_    512
#define NC    128      // [actor 64 | critic 64] hidden cols
#define NSLICE 8       // K-split
#define PADK  136      // halfwords per wT row (128 + 8 pad)
#define TWO_LOG2E 2.8853900817779268f

typedef __attribute__((ext_vector_type(8))) short bf16x8;
typedef __attribute__((ext_vector_type(4))) float f32x4;

__device__ __forceinline__ float fast_tanh(float x) {
    return 1.0f - 2.0f / (__expf(2.0f * x) + 1.0f);
}

// tanh where z is PRE-SCALED by 2*log2(e)
__device__ __forceinline__ float tanh_exp2(float z) {
    return 1.0f - 2.0f / (__builtin_amdgcn_exp2f(z) + 1.0f);
}

__device__ __forceinline__ unsigned short rne_bf16(float f) {
    union { float f; unsigned u; } v; v.f = f;
    unsigned u = v.u;
    return (unsigned short)((u + 0x7FFFu + ((u >> 16) & 1u)) >> 16);
}

__device__ __forceinline__ unsigned pack_bf16(float lo, float hi) {
    return (unsigned)rne_bf16(lo) | ((unsigned)rne_bf16(hi) << 16);
}

__device__ __forceinline__ unsigned short to_bf16u(float f) {
    __hip_bfloat16 h = __float2bfloat16(f);   // RNE, compiler-optimized cvt
    return *reinterpret_cast<unsigned short*>(&h);
}

__device__ __forceinline__ short to_bf16(float f) {
    __hip_bfloat16 h = __float2bfloat16(f);
    return *reinterpret_cast<short*>(&h);
}

__device__ __forceinline__ float bf16_lo(unsigned p) { return __uint_as_float(p << 16); }
__device__ __forceinline__ float bf16_hi(unsigned p) { return __uint_as_float(p & 0xffff0000u); }
__device__ __forceinline__ float bf16_f(unsigned short v) { return __uint_as_float(((unsigned)v) << 16); }

// broadcast register value from lane k (compile-time k) via SGPR, no LDS
#define RL(x, k) __int_as_float(__builtin_amdgcn_readlane(__float_as_int(x), (k)))

// ws layout (bytes): vTp 8K | W2p 8K | Wfp 8K | Wc2p 8K | partials 4MB (bf16)
#define WS_VTP   0
#define WS_W2P   8192
#define WS_WFP   16384
#define WS_WC2P  24576
#define WS_PART  32768

// ---------------- Kernel 1: self-contained MFMA GEMM, 8-way K-split -----------
__global__ __launch_bounds__(256) void k1_mfma(
        const float* __restrict__ x, const float* __restrict__ W1,
        const float* __restrict__ Wc1, const float* __restrict__ emb,
        const float* __restrict__ We, const float* __restrict__ W2,
        const float* __restrict__ Wf, const float* __restrict__ Wc2,
        unsigned char* __restrict__ ws) {
    __shared__ unsigned short wT[128 * PADK];   // 34.8 KB
    const int tid    = threadIdx.x;
    const int bid    = blockIdx.x;
    const int mb     = bid >> 3;                // rows mb*32
    const int kslice = bid & 7;
    const int k0     = kslice * 128;

    const int w = tid >> 6;
    const int l = tid & 63;
    const int c = l & 15;
    const int g = l >> 4;

    // ---- prefetch ALL x for this wave into registers (hides HBM latency
    //      under the W staging phase) ----
    const float* xrow0 = x + (size_t)(mb * 32 + c) * OBS_ + k0 + g * 8;
    const float* xrow1 = xrow0 + (size_t)16 * OBS_;
    float4 xa[4][2], xb[4][2];
    #pragma unroll
    for (int ks = 0; ks < 4; ++ks) {
        xa[ks][0] = ((const float4*)(xrow0 + ks * 32))[0];
        xa[ks][1] = ((const float4*)(xrow0 + ks * 32))[1];
        xb[ks][0] = ((const float4*)(xrow1 + ks * 32))[0];
        xb[ks][1] = ((const float4*)(xrow1 + ks * 32))[1];
    }

    // ---- stage W[k0..k0+128)[0..128) -> wT[n][kk] bf16 (cvt-based pack) ----
    {
        const int n  = tid & 127;
        const int th = tid >> 7;                 // 0..1
        const float* src = (n < 64) ? (W1 + n) : (Wc1 + (n - 64));
        #pragma unroll
        for (int gg = 0; gg < 16; ++gg) {
            int kq = gg * 2 + th;                // 0..31
            int k  = k0 + kq * 4;
            ushort4 hv;
            hv.x = to_bf16u(src[(size_t)(k + 0) * 64]);
            hv.y = to_bf16u(src[(size_t)(k + 1) * 64]);
            hv.z = to_bf16u(src[(size_t)(k + 2) * 64]);
            hv.w = to_bf16u(src[(size_t)(k + 3) * 64]);
            *reinterpret_cast<ushort4*>(&wT[n * PADK + kq * 4]) = hv;
        }
    }
    __syncthreads();

    // ---- MFMA: 4 K-iters, 2 ntiles x 2 row-tiles per wave ----
    const int nt0 = 2 * w, nt1 = 2 * w + 1;
    const unsigned short* bp0 = &wT[(nt0 * 16 + c) * PADK + g * 8];
    const unsigned short* bp1 = &wT[(nt1 * 16 + c) * PADK + g * 8];

    f32x4 acc00 = {0.f, 0.f, 0.f, 0.f};
    f32x4 acc01 = {0.f, 0.f, 0.f, 0.f};
    f32x4 acc10 = {0.f, 0.f, 0.f, 0.f};
    f32x4 acc11 = {0.f, 0.f, 0.f, 0.f};
    #pragma unroll
    for (int ks = 0; ks < 4; ++ks) {
        float4 a0 = xa[ks][0], a1 = xa[ks][1];
        float4 b0 = xb[ks][0], b1 = xb[ks][1];
        bf16x8 av0, av1;
        av0[0] = to_bf16(a0.x); av0[1] = to_bf16(a0.y);
        av0[2] = to_bf16(a0.z); av0[3] = to_bf16(a0.w);
        av0[4] = to_bf16(a1.x); av0[5] = to_bf16(a1.y);
        av0[6] = to_bf16(a1.z); av0[7] = to_bf16(a1.w);
        av1[0] = to_bf16(b0.x); av1[1] = to_bf16(b0.y);
        av1[2] = to_bf16(b0.z); av1[3] = to_bf16(b0.w);
        av1[4] = to_bf16(b1.x); av1[5] = to_bf16(b1.y);
        av1[6] = to_bf16(b1.z); av1[7] = to_bf16(b1.w);
        bf16x8 bv0 = *(const bf16x8*)(bp0 + ks * 32);
        bf16x8 bv1 = *(const bf16x8*)(bp1 + ks * 32);
        acc00 = __builtin_amdgcn_mfma_f32_16x16x32_bf16(av0, bv0, acc00, 0, 0, 0);
        acc01 = __builtin_amdgcn_mfma_f32_16x16x32_bf16(av0, bv1, acc01, 0, 0, 0);
        acc10 = __builtin_amdgcn_mfma_f32_16x16x32_bf16(av1, bv0, acc10, 0, 0, 0);
        acc11 = __builtin_amdgcn_mfma_f32_16x16x32_bf16(av1, bv1, acc11, 0, 0, 0);
    }

    // C/D layout: col = lane&15, row = (lane>>4)*4 + reg
    // partials bf16 [row][kslice][col]
    unsigned short* pbase = (unsigned short*)(ws + WS_PART);
    const int col0 = nt0 * 16 + c;
    const int col1 = nt1 * 16 + c;
    const int r0   = mb * 32 + g * 4;
    const int r1   = r0 + 16;
    #pragma unroll
    for (int r = 0; r < 4; ++r) {
        pbase[((size_t)(r0 + r) * NSLICE + kslice) * NC + col0] = to_bf16u(acc00[r]);
        pbase[((size_t)(r0 + r) * NSLICE + kslice) * NC + col1] = to_bf16u(acc01[r]);
        pbase[((size_t)(r1 + r) * NSLICE + kslice) * NC + col0] = to_bf16u(acc10[r]);
        pbase[((size_t)(r1 + r) * NSLICE + kslice) * NC + col1] = to_bf16u(acc11[r]);
    }

    // ---- tail: pre-pack k2 weight tables (blocks 0..31) ----
    if (bid < 32) {
        const int job = bid >> 3;               // 0:vTp 1:W2p 2:Wfp 3:Wc2p
        const int idx = (bid & 7) * 256 + tid;  // 0..2047
        if (job == 0) {
            int hp = idx >> 6, t = idx & 63;
            float s0 = 0.f, s1 = 0.f;
            #pragma unroll
            for (int e = 0; e < 16; ++e) {
                float ev = emb[t * 16 + e];
                s0 += ev * We[e * 64 + 2 * hp];
                s1 += ev * We[e * 64 + 2 * hp + 1];
            }
            ((unsigned*)(ws + WS_VTP))[idx] = pack_bf16(s0 * TWO_LOG2E, s1 * TWO_LOG2E);
        } else {
            const float* src = (job == 1) ? W2 : (job == 2) ? Wf : Wc2;
            unsigned* dst = (unsigned*)(ws + ((job == 1) ? WS_W2P : (job == 2) ? WS_WFP : WS_WC2P));
            int rp = idx >> 6, hh = idx & 63;
            dst[idx] = pack_bf16(src[(2 * rp) * 64 + hh], src[(2 * rp + 1) * 64 + hh]);
        }
    }
}

// ---------------- Kernel 2: per-row fused head (1 wave = 1 batch row) ---------
// 256 blocks x 512 threads; input loads hoisted above table staging.
__global__ __launch_bounds__(512) void k2_score(
        const unsigned char* __restrict__ ws,
        const int* __restrict__ action_types, const int* __restrict__ action_counts,
        const int* __restrict__ action,
        const float* __restrict__ b1, const float* __restrict__ bc1,
        const float* __restrict__ b2, const float* __restrict__ ba,
        const float* __restrict__ Wo, const float* __restrict__ bo,
        const float* __restrict__ bc2, const float* __restrict__ Wc3,
        const float* __restrict__ bc3, float* __restrict__ out) {
    __shared__ unsigned sW2p[32][64];
    __shared__ unsigned sWfp[32][64];
    __shared__ unsigned sWc2p[32][64];
    __shared__ unsigned sVTp[32][64];
    __shared__ int scnt[8][64];

    const int tid  = threadIdx.x;
    const int lane = tid & 63;
    const int wid  = tid >> 6;           // 0..7
    const int b    = blockIdx.x * 8 + wid;

    // ---- hoisted input loads (latency hides under table staging) ----
    const unsigned short* pa = (const unsigned short*)(ws + WS_PART)
                             + (size_t)b * NSLICE * NC + lane;
    unsigned short pr[NSLICE], pcr[NSLICE];
    #pragma unroll
    for (int s8 = 0; s8 < NSLICE; ++s8) {
        pr[s8]  = pa[s8 * NC];
        pcr[s8] = pa[s8 * NC + 64];
    }
    const int* at_row = action_types + (size_t)b * A_;
    const int a_star = action[b];
    const int count  = action_counts[b];
    const int base   = lane * 8;
    int4 p0 = *reinterpret_cast<const int4*>(at_row + base);
    int4 p1 = *reinterpret_cast<const int4*>(at_row + base + 4);
    const int t_star = at_row[a_star] & 63;

    // ---- stage tables ----
    {
        const unsigned* gV = (const unsigned*)(ws + WS_VTP);
        const unsigned* g2 = (const unsigned*)(ws + WS_W2P);
        const unsigned* gF = (const unsigned*)(ws + WS_WFP);
        const unsigned* gC = (const unsigned*)(ws + WS_WC2P);
        #pragma unroll
        for (int i = 0; i < 4; ++i) {
            int idx = tid + i * 512;
            ((unsigned*)sVTp)[idx]  = gV[idx];
            ((unsigned*)sW2p)[idx]  = g2[idx];
            ((unsigned*)sWfp)[idx]  = gF[idx];
            ((unsigned*)sWc2p)[idx] = gC[idx];
        }
    }
    scnt[wid][lane] = 0;
    __syncthreads();

    // sum 8 bf16 K-split partials, bias, tanh (2-way ILP)
    float h1a = 0.f, h1b = 0.f, c1a = 0.f, c1b = 0.f;
    #pragma unroll
    for (int s8 = 0; s8 < NSLICE; s8 += 2) {
        h1a += bf16_f(pr[s8]);
        h1b += bf16_f(pr[s8 + 1]);
        c1a += bf16_f(pcr[s8]);
        c1b += bf16_f(pcr[s8 + 1]);
    }
    float h1v = fast_tanh(h1a + h1b + b1[lane]);
    float c1v = fast_tanh(c1a + c1b + bc1[lane]);

    // feats[h] = tanh(sum_k h1[k]*W2[k][h] + b2[h])  (4 accumulator chains)
    float f0 = b2[lane], f1 = 0.f, f2 = 0.f, f3 = 0.f;
    #pragma unroll
    for (int kp = 0; kp < 32; kp += 2) {
        unsigned pwA = sW2p[kp][lane];
        unsigned pwB = sW2p[kp + 1][lane];
        f0 += RL(h1v, 2 * kp)     * bf16_lo(pwA);
        f1 += RL(h1v, 2 * kp + 1) * bf16_hi(pwA);
        f2 += RL(h1v, 2 * kp + 2) * bf16_lo(pwB);
        f3 += RL(h1v, 2 * kp + 3) * bf16_hi(pwB);
    }
    const float f = fast_tanh((f0 + f1) + (f2 + f3));

    // u[h] = sum_k feats[k]*Wf[k][h] + ba[h]
    float u0 = ba[lane], u1 = 0.f, u2 = 0.f, u3 = 0.f;
    #pragma unroll
    for (int kp = 0; kp < 32; kp += 2) {
        unsigned pwA = sWfp[kp][lane];
        unsigned pwB = sWfp[kp + 1][lane];
        u0 += RL(f, 2 * kp)     * bf16_lo(pwA);
        u1 += RL(f, 2 * kp + 1) * bf16_hi(pwA);
        u2 += RL(f, 2 * kp + 2) * bf16_lo(pwB);
        u3 += RL(f, 2 * kp + 3) * bf16_hi(pwB);
    }
    const float u = ((u0 + u1) + (u2 + u3)) * TWO_LOG2E;

    // critic: cc = tanh(c1@Wc2+bc2); value = cc.Wc3 + bc3
    float g0 = bc2[lane], g1 = 0.f, g2 = 0.f, g3 = 0.f;
    #pragma unroll
    for (int kp = 0; kp < 32; kp += 2) {
        unsigned pwA = sWc2p[kp][lane];
        unsigned pwB = sWc2p[kp + 1][lane];
        g0 += RL(c1v, 2 * kp)     * bf16_lo(pwA);
        g1 += RL(c1v, 2 * kp + 1) * bf16_hi(pwA);
        g2 += RL(c1v, 2 * kp + 2) * bf16_lo(pwB);
        g3 += RL(c1v, 2 * kp + 3) * bf16_hi(pwB);
    }
    float cc = fast_tanh((g0 + g1) + (g2 + g3));
    float pv = cc * Wc3[lane];
    #pragma unroll
    for (int off = 32; off > 0; off >>= 1) pv += __shfl_xor(pv, off);
    const float value = pv + bc3[0];

    // score-per-type: lane = t  (4 accumulator chains; vT pre-scaled)
    float s0 = bo[0], s1 = 0.f, s2 = 0.f, s3 = 0.f;
    #pragma unroll
    for (int hp = 0; hp < 32; hp += 2) {
        unsigned pvA = sVTp[hp][lane];
        unsigned pvB = sVTp[hp + 1][lane];
        s0 += tanh_exp2(RL(u, 2 * hp)     + bf16_lo(pvA)) * Wo[2 * hp];
        s1 += tanh_exp2(RL(u, 2 * hp + 1) + bf16_hi(pvA)) * Wo[2 * hp + 1];
        s2 += tanh_exp2(RL(u, 2 * hp + 2) + bf16_lo(pvB)) * Wo[2 * hp + 2];
        s3 += tanh_exp2(RL(u, 2 * hp + 3) + bf16_hi(pvB)) * Wo[2 * hp + 3];
    }
    const float s = (s0 + s1) + (s2 + s3);

    // histogram of valid action types (wave-private)
    int* cptr = scnt[wid];
    if (base + 0 < count) atomicAdd(&cptr[p0.x & 63], 1);
    if (base + 1 < count) atomicAdd(&cptr[p0.y & 63], 1);
    if (base + 2 < count) atomicAdd(&cptr[p0.z & 63], 1);
    if (base + 3 < count) atomicAdd(&cptr[p0.w & 63], 1);
    if (base + 4 < count) atomicAdd(&cptr[p1.x & 63], 1);
    if (base + 5 < count) atomicAdd(&cptr[p1.y & 63], 1);
    if (base + 6 < count) atomicAdd(&cptr[p1.z & 63], 1);
    if (base + 7 < count) atomicAdd(&cptr[p1.w & 63], 1);

    // softmax stats over 64 types weighted by counts
    const int cv = cptr[lane];
    float mval = (cv > 0) ? s : -3.0e38f;
    #pragma unroll
    for (int off = 32; off > 0; off >>= 1) mval = fmaxf(mval, __shfl_xor(mval, off));
    const float e  = (float)cv * __expf(s - mval);
    float se = e, sd = e * s;
    #pragma unroll
    for (int off = 32; off > 0; off >>= 1) {
        se += __shfl_xor(se, off);
        sd += __shfl_xor(sd, off);
    }
    const float logZ    = mval + __logf(se);
    const float entropy = logZ - sd / se;
    const float logp    = __shfl(s, t_star) - logZ;

    if (lane == 0) {
        out[b * 3 + 0] = logp;
        out[b * 3 + 1] = entropy;
        out[b * 3 + 2] = value;
    }
}

extern "C" void kernel_launch(void* const* d_in, const int* in_sizes, int n_in,
                              void* d_out, int out_size, void* d_ws, size_t ws_size,
                              hipStream_t stream) {
    const float* x             = (const float*)d_in[0];
    const int*   action_types  = (const int*)  d_in[1];
    const int*   action_counts = (const int*)  d_in[2];
    const int*   action        = (const int*)  d_in[3];
    const float* emb           = (const float*)d_in[4];
    const float* W1            = (const float*)d_in[5];
    const float* b1            = (const float*)d_in[6];
    const float* W2            = (const float*)d_in[7];
    const float* b2            = (const float*)d_in[8];
    const float* Wf            = (const float*)d_in[9];
    const float* We            = (const float*)d_in[10];
    const float* ba            = (const float*)d_in[11];
    const float* Wo            = (const float*)d_in[12];
    const float* bo            = (const float*)d_in[13];
    const float* Wc1           = (const float*)d_in[14];
    const float* bc1           = (const float*)d_in[15];
    const float* Wc2           = (const float*)d_in[16];
    const float* bc2           = (const float*)d_in[17];
    const float* Wc3           = (const float*)d_in[18];
    const float* bc3           = (const float*)d_in[19];
    float* out = (float*)d_out;
    unsigned char* ws = (unsigned char*)d_ws;

    k1_mfma<<<512, 256, 0, stream>>>(x, W1, Wc1, emb, We, W2, Wf, Wc2, ws);
    k2_score<<<256, 512, 0, stream>>>(ws, action_types, action_counts, action,
                                      b1, bc1, b2, ba, Wo, bo, bc2, Wc3, bc3, out);
}

// Round 14
// 23.994 us; speedup vs baseline: 1.0280x; 1.0280x over previous
//
#include <hip/hip_runtime.h>
#include <hip/hip_bf16.h>

#define B_    2048
#define OBS_  1024
#define A_    512
#define NC    128      // [actor 64 | critic 64] hidden cols
#define NSLICE 8       // K-split
#define PADK  136      // halfwords per wT row (128 + 8 pad)
#define TWO_LOG2E 2.8853900817779268f

typedef __attribute__((ext_vector_type(8))) short bf16x8;
typedef __attribute__((ext_vector_type(4))) float f32x4;

__device__ __forceinline__ float fast_tanh(float x) {
    return 1.0f - 2.0f / (__expf(2.0f * x) + 1.0f);
}

// tanh where z is PRE-SCALED by 2*log2(e): tanh(x) with z = x*2log2e
__device__ __forceinline__ float tanh_exp2(float z) {
    return 1.0f - 2.0f / (__builtin_amdgcn_exp2f(z) + 1.0f);
}

__device__ __forceinline__ unsigned short rne_bf16(float f) {
    union { float f; unsigned u; } v; v.f = f;
    unsigned u = v.u;
    return (unsigned short)((u + 0x7FFFu + ((u >> 16) & 1u)) >> 16);
}

__device__ __forceinline__ unsigned pack_bf16(float lo, float hi) {
    return (unsigned)rne_bf16(lo) | ((unsigned)rne_bf16(hi) << 16);
}

__device__ __forceinline__ short to_bf16(float f) {
    __hip_bfloat16 h = __float2bfloat16(f);   // RNE
    return *reinterpret_cast<short*>(&h);
}

__device__ __forceinline__ float bf16_lo(unsigned p) { return __uint_as_float(p << 16); }
__device__ __forceinline__ float bf16_hi(unsigned p) { return __uint_as_float(p & 0xffff0000u); }
__device__ __forceinline__ float bf16_f(unsigned short v) { return __uint_as_float(((unsigned)v) << 16); }

// broadcast register value from lane k (compile-time k) via SGPR, no LDS
#define RL(x, k) __int_as_float(__builtin_amdgcn_readlane(__float_as_int(x), (k)))

// ws layout (bytes): vTp 8K | W2p 8K | Wfp 8K | Wc2p 8K | partials 4MB (bf16)
#define WS_VTP   0
#define WS_W2P   8192
#define WS_WFP   16384
#define WS_WC2P  24576
#define WS_PART  32768

// ---------------- Kernel 1: self-contained MFMA GEMM, 8-way K-split -----------
// grid 512: mb = bid>>3 (32-row tile), kslice = bid&7 (128 K each)
// Stage W-slice fp32->bf16 into transposed LDS wT[n][kk]; each ds_read_b128
// B-fragment feeds 2 row-tiles (4 MFMAs). Partials stored bf16 [row][ks][col].
// Blocks 0..31 also pre-pack the bf16x2 weight tables consumed by k2
// (vT table pre-scaled by 2*log2e for k2's exp2-tanh).
__global__ __launch_bounds__(256) void k1_mfma(
        const float* __restrict__ x, const float* __restrict__ W1,
        const float* __restrict__ Wc1, const float* __restrict__ emb,
        const float* __restrict__ We, const float* __restrict__ W2,
        const float* __restrict__ Wf, const float* __restrict__ Wc2,
        unsigned char* __restrict__ ws) {
    __shared__ unsigned short wT[128 * PADK];   // 34.8 KB
    const int tid    = threadIdx.x;
    const int bid    = blockIdx.x;
    const int mb     = bid >> 3;                // 0..63 -> rows mb*32
    const int kslice = bid & 7;
    const int k0     = kslice * 128;

    // ---- stage W[k0..k0+128)[0..128) -> wT[n][kk] bf16 ----
    {
        const int n  = tid & 127;
        const int th = tid >> 7;                 // 0..1
        const float* src = (n < 64) ? (W1 + n) : (Wc1 + (n - 64));
        #pragma unroll
        for (int gg = 0; gg < 16; ++gg) {
            int kq = gg * 2 + th;                // 0..31
            int k  = k0 + kq * 4;
            float w0 = src[(size_t)(k + 0) * 64];
            float w1 = src[(size_t)(k + 1) * 64];
            float w2 = src[(size_t)(k + 2) * 64];
            float w3 = src[(size_t)(k + 3) * 64];
            unsigned long long v = (unsigned long long)pack_bf16(w0, w1)
                                 | ((unsigned long long)pack_bf16(w2, w3) << 32);
            *reinterpret_cast<unsigned long long*>(&wT[n * PADK + kq * 4]) = v;
        }
    }
    __syncthreads();

    // ---- MFMA: 4 K-iters, 2 ntiles x 2 row-tiles per wave ----
    const int w = tid >> 6;
    const int l = tid & 63;
    const int c = l & 15;
    const int g = l >> 4;

    const float* xrow0 = x + (size_t)(mb * 32 + c) * OBS_ + k0 + g * 8;
    const float* xrow1 = xrow0 + (size_t)16 * OBS_;
    const int nt0 = 2 * w, nt1 = 2 * w + 1;
    const unsigned short* bp0 = &wT[(nt0 * 16 + c) * PADK + g * 8];
    const unsigned short* bp1 = &wT[(nt1 * 16 + c) * PADK + g * 8];

    f32x4 acc00 = {0.f, 0.f, 0.f, 0.f};
    f32x4 acc01 = {0.f, 0.f, 0.f, 0.f};
    f32x4 acc10 = {0.f, 0.f, 0.f, 0.f};
    f32x4 acc11 = {0.f, 0.f, 0.f, 0.f};
    #pragma unroll
    for (int ks = 0; ks < 4; ++ks) {
        const float4* xp0 = (const float4*)(xrow0 + ks * 32);
        const float4* xp1 = (const float4*)(xrow1 + ks * 32);
        float4 a0 = xp0[0], a1 = xp0[1];
        float4 b0 = xp1[0], b1 = xp1[1];
        bf16x8 av0, av1;
        av0[0] = to_bf16(a0.x); av0[1] = to_bf16(a0.y);
        av0[2] = to_bf16(a0.z); av0[3] = to_bf16(a0.w);
        av0[4] = to_bf16(a1.x); av0[5] = to_bf16(a1.y);
        av0[6] = to_bf16(a1.z); av0[7] = to_bf16(a1.w);
        av1[0] = to_bf16(b0.x); av1[1] = to_bf16(b0.y);
        av1[2] = to_bf16(b0.z); av1[3] = to_bf16(b0.w);
        av1[4] = to_bf16(b1.x); av1[5] = to_bf16(b1.y);
        av1[6] = to_bf16(b1.z); av1[7] = to_bf16(b1.w);
        bf16x8 bv0 = *(const bf16x8*)(bp0 + ks * 32);
        bf16x8 bv1 = *(const bf16x8*)(bp1 + ks * 32);
        acc00 = __builtin_amdgcn_mfma_f32_16x16x32_bf16(av0, bv0, acc00, 0, 0, 0);
        acc01 = __builtin_amdgcn_mfma_f32_16x16x32_bf16(av0, bv1, acc01, 0, 0, 0);
        acc10 = __builtin_amdgcn_mfma_f32_16x16x32_bf16(av1, bv0, acc10, 0, 0, 0);
        acc11 = __builtin_amdgcn_mfma_f32_16x16x32_bf16(av1, bv1, acc11, 0, 0, 0);
    }

    // C/D layout: col = lane&15, row = (lane>>4)*4 + reg
    // partials bf16 [row][kslice][col]
    unsigned short* pbase = (unsigned short*)(ws + WS_PART);
    const int col0 = nt0 * 16 + c;
    const int col1 = nt1 * 16 + c;
    const int r0   = mb * 32 + g * 4;
    const int r1   = r0 + 16;
    #pragma unroll
    for (int r = 0; r < 4; ++r) {
        pbase[((size_t)(r0 + r) * NSLICE + kslice) * NC + col0] = (unsigned short)to_bf16(acc00[r]);
        pbase[((size_t)(r0 + r) * NSLICE + kslice) * NC + col1] = (unsigned short)to_bf16(acc01[r]);
        pbase[((size_t)(r1 + r) * NSLICE + kslice) * NC + col0] = (unsigned short)to_bf16(acc10[r]);
        pbase[((size_t)(r1 + r) * NSLICE + kslice) * NC + col1] = (unsigned short)to_bf16(acc11[r]);
    }

    // ---- tail: pre-pack k2 weight tables (blocks 0..31) ----
    if (bid < 32) {
        const int job = bid >> 3;               // 0:vTp 1:W2p 2:Wfp 3:Wc2p
        const int idx = (bid & 7) * 256 + tid;  // 0..2047
        if (job == 0) {
            int hp = idx >> 6, t = idx & 63;
            float s0 = 0.f, s1 = 0.f;
            #pragma unroll
            for (int e = 0; e < 16; ++e) {
                float ev = emb[t * 16 + e];
                s0 += ev * We[e * 64 + 2 * hp];
                s1 += ev * We[e * 64 + 2 * hp + 1];
            }
            // pre-scale by 2*log2e for k2's exp2-based tanh
            ((unsigned*)(ws + WS_VTP))[idx] = pack_bf16(s0 * TWO_LOG2E, s1 * TWO_LOG2E);
        } else {
            const float* src = (job == 1) ? W2 : (job == 2) ? Wf : Wc2;
            unsigned* dst = (unsigned*)(ws + ((job == 1) ? WS_W2P : (job == 2) ? WS_WFP : WS_WC2P));
            int rp = idx >> 6, hh = idx & 63;
            dst[idx] = pack_bf16(src[(2 * rp) * 64 + hh], src[(2 * rp + 1) * 64 + hh]);
        }
    }
}

// ---------------- Kernel 2: per-row fused head (1 wave = 1 batch row) ---------
// 256 blocks x 512 threads (8 waves): halves per-block table staging traffic.
__global__ __launch_bounds__(512) void k2_score(
        const unsigned char* __restrict__ ws,
        const int* __restrict__ action_types, const int* __restrict__ action_counts,
        const int* __restrict__ action,
        const float* __restrict__ b1, const float* __restrict__ bc1,
        const float* __restrict__ b2, const float* __restrict__ ba,
        const float* __restrict__ Wo, const float* __restrict__ bo,
        const float* __restrict__ bc2, const float* __restrict__ Wc3,
        const float* __restrict__ bc3, float* __restrict__ out) {
    __shared__ unsigned sW2p[32][64];
    __shared__ unsigned sWfp[32][64];
    __shared__ unsigned sWc2p[32][64];
    __shared__ unsigned sVTp[32][64];
    __shared__ int scnt[8][64];

    const int tid = threadIdx.x;
    {
        const unsigned* gV = (const unsigned*)(ws + WS_VTP);
        const unsigned* g2 = (const unsigned*)(ws + WS_W2P);
        const unsigned* gF = (const unsigned*)(ws + WS_WFP);
        const unsigned* gC = (const unsigned*)(ws + WS_WC2P);
        #pragma unroll
        for (int i = 0; i < 4; ++i) {
            int idx = tid + i * 512;
            ((unsigned*)sVTp)[idx]  = gV[idx];
            ((unsigned*)sW2p)[idx]  = g2[idx];
            ((unsigned*)sWfp)[idx]  = gF[idx];
            ((unsigned*)sWc2p)[idx] = gC[idx];
        }
    }
    scnt[tid >> 6][tid & 63] = 0;
    __syncthreads();

    const int lane = tid & 63;
    const int wid  = tid >> 6;           // 0..7
    const int b    = blockIdx.x * 8 + wid;

    // sum 8 bf16 K-split partials [row][ks][col], bias, tanh (2-way ILP)
    const unsigned short* pa = (const unsigned short*)(ws + WS_PART)
                             + (size_t)b * NSLICE * NC + lane;
    float h1a = 0.f, h1b = 0.f, c1a = 0.f, c1b = 0.f;
    #pragma unroll
    for (int s8 = 0; s8 < NSLICE; s8 += 2) {
        h1a += bf16_f(pa[s8 * NC]);
        h1b += bf16_f(pa[(s8 + 1) * NC]);
        c1a += bf16_f(pa[s8 * NC + 64]);
        c1b += bf16_f(pa[(s8 + 1) * NC + 64]);
    }
    float h1v = fast_tanh(h1a + h1b + b1[lane]);
    float c1v = fast_tanh(c1a + c1b + bc1[lane]);

    const int* at_row = action_types + (size_t)b * A_;
    const int count = action_counts[b];
    const int base = lane * 8;
    int4 p0 = *reinterpret_cast<const int4*>(at_row + base);
    int4 p1 = *reinterpret_cast<const int4*>(at_row + base + 4);
    const int a_star = action[b];
    const int t_star = at_row[a_star] & 63;

    // feats[h] = tanh(sum_k h1[k]*W2[k][h] + b2[h])  (4 accumulator chains)
    float f0 = b2[lane], f1 = 0.f, f2 = 0.f, f3 = 0.f;
    #pragma unroll
    for (int kp = 0; kp < 32; kp += 2) {
        unsigned pwA = sW2p[kp][lane];
        unsigned pwB = sW2p[kp + 1][lane];
        f0 += RL(h1v, 2 * kp)     * bf16_lo(pwA);
        f1 += RL(h1v, 2 * kp + 1) * bf16_hi(pwA);
        f2 += RL(h1v, 2 * kp + 2) * bf16_lo(pwB);
        f3 += RL(h1v, 2 * kp + 3) * bf16_hi(pwB);
    }
    const float f = fast_tanh((f0 + f1) + (f2 + f3));

    // u[h] = sum_k feats[k]*Wf[k][h] + ba[h]
    float u0 = ba[lane], u1 = 0.f, u2 = 0.f, u3 = 0.f;
    #pragma unroll
    for (int kp = 0; kp < 32; kp += 2) {
        unsigned pwA = sWfp[kp][lane];
        unsigned pwB = sWfp[kp + 1][lane];
        u0 += RL(f, 2 * kp)     * bf16_lo(pwA);
        u1 += RL(f, 2 * kp + 1) * bf16_hi(pwA);
        u2 += RL(f, 2 * kp + 2) * bf16_lo(pwB);
        u3 += RL(f, 2 * kp + 3) * bf16_hi(pwB);
    }
    // pre-scale u by 2*log2e so the score loop uses native exp2 tanh
    const float u = ((u0 + u1) + (u2 + u3)) * TWO_LOG2E;

    // critic: cc = tanh(c1@Wc2+bc2); value = cc.Wc3 + bc3
    float g0 = bc2[lane], g1 = 0.f, g2 = 0.f, g3 = 0.f;
    #pragma unroll
    for (int kp = 0; kp < 32; kp += 2) {
        unsigned pwA = sWc2p[kp][lane];
        unsigned pwB = sWc2p[kp + 1][lane];
        g0 += RL(c1v, 2 * kp)     * bf16_lo(pwA);
        g1 += RL(c1v, 2 * kp + 1) * bf16_hi(pwA);
        g2 += RL(c1v, 2 * kp + 2) * bf16_lo(pwB);
        g3 += RL(c1v, 2 * kp + 3) * bf16_hi(pwB);
    }
    float cc = fast_tanh((g0 + g1) + (g2 + g3));
    float pv = cc * Wc3[lane];
    #pragma unroll
    for (int off = 32; off > 0; off >>= 1) pv += __shfl_xor(pv, off);
    const float value = pv + bc3[0];

    // score-per-type: lane = t  (4 accumulator chains; vT pre-scaled)
    float s0 = bo[0], s1 = 0.f, s2 = 0.f, s3 = 0.f;
    #pragma unroll
    for (int hp = 0; hp < 32; hp += 2) {
        unsigned pvA = sVTp[hp][lane];
        unsigned pvB = sVTp[hp + 1][lane];
        s0 += tanh_exp2(RL(u, 2 * hp)     + bf16_lo(pvA)) * Wo[2 * hp];
        s1 += tanh_exp2(RL(u, 2 * hp + 1) + bf16_hi(pvA)) * Wo[2 * hp + 1];
        s2 += tanh_exp2(RL(u, 2 * hp + 2) + bf16_lo(pvB)) * Wo[2 * hp + 2];
        s3 += tanh_exp2(RL(u, 2 * hp + 3) + bf16_hi(pvB)) * Wo[2 * hp + 3];
    }
    const float s = (s0 + s1) + (s2 + s3);

    // histogram of valid action types (wave-private)
    int* cptr = scnt[wid];
    if (base + 0 < count) atomicAdd(&cptr[p0.x & 63], 1);
    if (base + 1 < count) atomicAdd(&cptr[p0.y & 63], 1);
    if (base + 2 < count) atomicAdd(&cptr[p0.z & 63], 1);
    if (base + 3 < count) atomicAdd(&cptr[p0.w & 63], 1);
    if (base + 4 < count) atomicAdd(&cptr[p1.x & 63], 1);
    if (base + 5 < count) atomicAdd(&cptr[p1.y & 63], 1);
    if (base + 6 < count) atomicAdd(&cptr[p1.z & 63], 1);
    if (base + 7 < count) atomicAdd(&cptr[p1.w & 63], 1);

    // softmax stats over 64 types weighted by counts
    const int cv = cptr[lane];
    float mval = (cv > 0) ? s : -3.0e38f;
    #pragma unroll
    for (int off = 32; off > 0; off >>= 1) mval = fmaxf(mval, __shfl_xor(mval, off));
    const float e  = (float)cv * __expf(s - mval);
    float se = e, sd = e * s;
    #pragma unroll
    for (int off = 32; off > 0; off >>= 1) {
        se += __shfl_xor(se, off);
        sd += __shfl_xor(sd, off);
    }
    const float logZ    = mval + __logf(se);
    const float entropy = logZ - sd / se;
    const float logp    = __shfl(s, t_star) - logZ;

    if (lane == 0) {
        out[b * 3 + 0] = logp;
        out[b * 3 + 1] = entropy;
        out[b * 3 + 2] = value;
    }
}

extern "C" void kernel_launch(void* const* d_in, const int* in_sizes, int n_in,
                              void* d_out, int out_size, void* d_ws, size_t ws_size,
                              hipStream_t stream) {
    const float* x             = (const float*)d_in[0];
    const int*   action_types  = (const int*)  d_in[1];
    const int*   action_counts = (const int*)  d_in[2];
    const int*   action        = (const int*)  d_in[3];
    const float* emb           = (const float*)d_in[4];
    const float* W1            = (const float*)d_in[5];
    const float* b1            = (const float*)d_in[6];
    const float* W2            = (const float*)d_in[7];
    const float* b2            = (const float*)d_in[8];
    const float* Wf            = (const float*)d_in[9];
    const float* We            = (const float*)d_in[10];
    const float* ba            = (const float*)d_in[11];
    const float* Wo            = (const float*)d_in[12];
    const float* bo            = (const float*)d_in[13];
    const float* Wc1           = (const float*)d_in[14];
    const float* bc1           = (const float*)d_in[15];
    const float* Wc2           = (const float*)d_in[16];
    const float* bc2           = (const float*)d_in[17];
    const float* Wc3           = (const float*)d_in[18];
    const float* bc3           = (const float*)d_in[19];
    float* out = (float*)d_out;
    unsigned char* ws = (unsigned char*)d_ws;

    k1_mfma<<<512, 256, 0, stream>>>(x, W1, Wc1, emb, We, W2, Wf, Wc2, ws);
    k2_score<<<256, 512, 0, stream>>>(ws, action_types, action_counts, action,
                                      b1, bc1, b2, ba, Wo, bo, bc2, Wc3, bc3, out);
}